// Round 1
// baseline (450.892 us; speedup 1.0000x reference)
//
#include <hip/hip_runtime.h>
#include <stdint.h>

#define IN_F  4096
#define OUT_F 4096
#define MROWS 8192            // 4 * 2048

typedef __bf16 bf16x8 __attribute__((ext_vector_type(8)));
typedef float  f32x4  __attribute__((ext_vector_type(4)));

// ---------------- numeric helpers (replicate reference rounding) -----------

__device__ __forceinline__ float e4m3_round_dev(float x) {
    x = fminf(x, 448.0f);                 // x >= 0 by construction (amax)
    float lo, hi;
    if (x < 0.015625f) {                  // below 2^-6: denormal grid, step 2^-9
        lo = floorf(x * 512.0f) * 0.001953125f;
        hi = lo + 0.001953125f;
    } else {
        unsigned u = __float_as_uint(x);
        int E = (int)((u >> 23) & 0xFF) - 127;                    // 2^E <= x < 2^(E+1)
        float step  = __uint_as_float((unsigned)(E + 124) << 23); // 2^(E-3)
        float istep = __uint_as_float((unsigned)(130 - E) << 23); // 2^(3-E), exact
        lo = floorf(x * istep) * step;    // exact pow2 scaling
        hi = lo + step;
    }
    return (x - lo <= hi - x) ? lo : hi;
}

__device__ __forceinline__ float e4m3_decode_dev(int bits) {
    int e = (bits >> 3) & 15;
    int m = bits & 7;
    float mag;
    if (e == 0) mag = (float)m * 0.001953125f;  // m/8 * 2^-6
    else        mag = (1.0f + (float)m * 0.125f) * __uint_as_float((unsigned)(e + 120) << 23); // 2^(e-7)
    return (bits & 0x80) ? -mag : mag;
}

__device__ __forceinline__ float fp4_round_dev(float y) {
    float a = fminf(fabsf(y), 6.0f);
    float v;
    if (a < 1.75f) {
        if (a < 0.75f) v = (a < 0.25f) ? 0.0f : 0.5f;
        else           v = (a < 1.25f) ? 1.0f : 1.5f;
    } else {
        if (a < 3.5f)  v = (a < 2.5f) ? 2.0f : 3.0f;
        else           v = (a < 5.0f) ? 4.0f : 6.0f;
    }
    return copysignf(v, y);
}

__device__ __forceinline__ float fp4_decode_dev(int c) {
    int e = (c >> 1) & 3, m = c & 1;
    float mag = (e == 0) ? 0.5f * (float)m
                         : (1.0f + 0.5f * (float)m) * __uint_as_float((unsigned)(e + 126) << 23); // 2^(e-1)
    return (c & 8) ? -mag : mag;
}

__device__ __forceinline__ unsigned pack_bf16x2(float a, float b) {
    return (__float_as_uint(a) >> 16) | ((__float_as_uint(b) >> 16) << 16);
}

// ---------------- kernel 1: activation quant-dequant (verified) ------------
__global__ __launch_bounds__(256) void quant_act_kernel(
    const float* __restrict__ x, const float* __restrict__ in_scale,
    unsigned short* __restrict__ Aq)
{
    int t = blockIdx.x * 256 + threadIdx.x;   // thread id; 4 elems each
    const float isc = in_scale[0];
    float4 v = ((const float4*)x)[t];

    float a = fmaxf(fmaxf(fabsf(v.x), fabsf(v.y)), fmaxf(fabsf(v.z), fabsf(v.w)));
    a = fmaxf(a, __shfl_xor(a, 1));
    a = fmaxf(a, __shfl_xor(a, 2));           // group (4 lanes) amax

    float bscale = e4m3_round_dev(a / (6.0f * isc));  // IEEE div, as reference
    float eff = bscale * isc;
    float safe = (eff > 0.0f) ? eff : 1.0f;
    float inv = 1.0f / safe;                          // IEEE div

    unsigned o0 = pack_bf16x2(fp4_round_dev(v.x * inv) * bscale,
                              fp4_round_dev(v.y * inv) * bscale);
    unsigned o1 = pack_bf16x2(fp4_round_dev(v.z * inv) * bscale,
                              fp4_round_dev(v.w * inv) * bscale);
    ((uint2*)Aq)[t] = make_uint2(o0, o1);
}

// ---------------- kernel 2: weight dequant (verified) ----------------------
__global__ __launch_bounds__(256) void dequant_w_kernel(
    const int* __restrict__ wq, const int* __restrict__ wsb,
    unsigned short* __restrict__ Wd)
{
    int t = blockIdx.x * 256 + threadIdx.x;
    float scale = e4m3_decode_dev(wsb[t >> 1]);
    int4 b = ((const int4*)wq)[t];
    int bytes[4] = { b.x, b.y, b.z, b.w };
    unsigned out[4];
    #pragma unroll
    for (int i = 0; i < 4; i++) {
        int by = bytes[i];
        float v0 = fp4_decode_dev(by & 15) * scale;
        float v1 = fp4_decode_dev((by >> 4) & 15) * scale;
        out[i] = pack_bf16x2(v0, v1);
    }
    ((uint4*)Wd)[t] = make_uint4(out[0], out[1], out[2], out[3]);
}

// ---------------- kernel 3: bf16 GEMM, 256x256 tile, 8-phase pipeline ------
//
// C[m,n] = s * sum_k A'[m,k] * W'[n,k],  s = input_scale * ws2
//
// 512 threads = 8 waves (2 M x 4 N); per-wave output 128x64.
// LDS 128 KiB: A,B each 2 parities x 2 half-slots of [128 rows][64 cols] bf16.
// Half-tile stream per K-tile t: #4t+q, q: 0=B-h0 1=B-h1 2=A-h0 3=A-h1.
// Phase g (g = 4t + j) stages half-tile #g+7; prologue pre-issues #0..6.
// vmcnt(6) once per K-tile (phase j=3): issued thru #4t+6 -> 3 half-tiles
// (6 loads) in flight -> #4t+3 (all of tile t) complete before tile t's reads.
// Slot-overwrite deadlines honored by read placement:
//   B-h0 read @ j0 (overwritten j1) ; B-h1 @ j0/j1 (ovw j2) ;
//   A-h0 @ j0/j2 (ovw j3) ; A-h1 @ j0/j2 (ovw next-iter j0).
// Reads drain at each phase's lgkmcnt(0) BEFORE the second barrier; the
// overwriting global_load_lds issues only after that barrier -> no race.
// XOR chunk swizzle (kc ^ row&7) on the global-source side, same scheme the
// verified 128^2 kernel used: ds_read_b128 lands at the 8-access/bank floor.

__device__ __forceinline__ void gload16(const void* g, void* l) {
    __builtin_amdgcn_global_load_lds((__attribute__((address_space(1))) void*)g,
                                     (__attribute__((address_space(3))) void*)l,
                                     16, 0, 0);
}

#define BARRIER() __builtin_amdgcn_s_barrier()
#define WAIT_LGKM0() do { asm volatile("s_waitcnt lgkmcnt(0)" ::: "memory"); \
                          __builtin_amdgcn_sched_barrier(0); } while (0)
#define WAIT_VM(n) asm volatile("s_waitcnt vmcnt(" #n ")" ::: "memory")

// stage half-tile q (0=B-h0,1=B-h1,2=A-h0,3=A-h1), buffer parity par,
// K-tile offset dt (in tiles) from the current pointer base.
#define STAGE(q, par, dt) do {                                                 \
    const unsigned short* g_ = ((q) >= 2 ? gA[(q)-2] : gB[(q)]) + (dt) * 64;   \
    char* l_ = ldsb + ((q) >= 2 ? (par)*32768 + ((q)-2)*16384                  \
                                : 65536 + (par)*32768 + (q)*16384) + ldst0;    \
    gload16(g_, l_);                                                           \
    gload16(g_ + CH2, l_ + 8192);                                              \
} while (0)

#define LOADA(par, qm) do {                                                    \
    const char* pa_ = ldsb + (par)*32768 + aRd + (qm)*8192;                    \
    _Pragma("unroll") for (int m_ = 0; m_ < 4; ++m_) {                         \
        af[m_][0] = *(const bf16x8*)(pa_ + m_*2048 + sw0);                     \
        af[m_][1] = *(const bf16x8*)(pa_ + m_*2048 + (sw0 ^ 64));              \
    }                                                                          \
} while (0)

#define LOADB01(par) do {                                                      \
    const char* pb_ = ldsb + (par)*32768 + bRd;                                \
    _Pragma("unroll") for (int n_ = 0; n_ < 2; ++n_) {                         \
        bf[n_][0] = *(const bf16x8*)(pb_ + n_*2048 + sw0);                     \
        bf[n_][1] = *(const bf16x8*)(pb_ + n_*2048 + (sw0 ^ 64));              \
    }                                                                          \
} while (0)

#define LOADB23(par) do {                                                      \
    const char* pb_ = ldsb + (par)*32768 + bRd;                                \
    _Pragma("unroll") for (int n_ = 2; n_ < 4; ++n_) {                         \
        bf[n_][0] = *(const bf16x8*)(pb_ + n_*2048 + sw0);                     \
        bf[n_][1] = *(const bf16x8*)(pb_ + n_*2048 + (sw0 ^ 64));              \
    }                                                                          \
} while (0)

#define MFMAQ(qm, qn) do {                                                     \
    __builtin_amdgcn_s_setprio(1);                                             \
    _Pragma("unroll") for (int m_ = 0; m_ < 4; ++m_)                           \
      _Pragma("unroll") for (int n_ = 0; n_ < 2; ++n_)                         \
        _Pragma("unroll") for (int kh_ = 0; kh_ < 2; ++kh_)                    \
          acc[(qm)*4 + m_][(qn)*2 + n_] =                                      \
            __builtin_amdgcn_mfma_f32_16x16x32_bf16(                           \
              af[m_][kh_], bf[(qn)*2 + n_][kh_],                               \
              acc[(qm)*4 + m_][(qn)*2 + n_], 0, 0, 0);                         \
    __builtin_amdgcn_s_setprio(0);                                             \
} while (0)

// One K-tile = 4 phases. DT = t - tt (0 or 1) for stage pointer offsets.
// S0: stage at phase 0 (next tile's A-h1). S123: stages at phases 1-3
// (tile t+2's B-h0/B-h1/A-h0). VMODE: 6 = steady, 0 = drain, -1 = none.
#define KTILE(par, DT, S0, S123, VMODE) do {                                   \
    /* phase 0: reads B01+A(half0) | stage #4t+7 | Q(0,0) */                   \
    LOADB01(par); LOADA(par, 0);                                               \
    if (S0) STAGE(3, (par) ^ 1, (DT) + 1);                                     \
    BARRIER(); WAIT_LGKM0();                                                   \
    MFMAQ(0, 0);                                                               \
    BARRIER();                                                                 \
    /* phase 1: reads B23 | stage #4t+8 | Q(0,1) */                            \
    LOADB23(par);                                                              \
    if (S123) STAGE(0, (par), (DT) + 2);                                       \
    BARRIER(); WAIT_LGKM0();                                                   \
    MFMAQ(0, 1);                                                               \
    BARRIER();                                                                 \
    /* phase 2: reads A(half1) | stage #4t+9 | Q(1,0) */                       \
    LOADA(par, 1);                                                             \
    if (S123) STAGE(1, (par), (DT) + 2);                                       \
    BARRIER(); WAIT_LGKM0();                                                   \
    MFMAQ(1, 0);                                                               \
    BARRIER();                                                                 \
    /* phase 3: stage #4t+10 | counted vmcnt | Q(1,1) */                       \
    if (S123) STAGE(2, (par), (DT) + 2);                                       \
    if ((VMODE) == 6) { WAIT_VM(6); } else if ((VMODE) == 0) { WAIT_VM(0); }   \
    BARRIER(); WAIT_LGKM0();                                                   \
    MFMAQ(1, 1);                                                               \
    BARRIER();                                                                 \
} while (0)

__global__ __launch_bounds__(512, 2) void gemm256(
    const unsigned short* __restrict__ A, const unsigned short* __restrict__ B,
    float* __restrict__ C, const float* __restrict__ isc,
    const float* __restrict__ ws2)
{
    extern __shared__ __align__(16) char lds[];
    char* const ldsb = lds;

    const int tid  = threadIdx.x;
    const int lane = tid & 63;
    const int w    = tid >> 6;          // 0..7
    const int wm   = w >> 2;            // 0..1  (M half)
    const int wn   = w & 3;             // 0..3  (N quarter)

    // XCD-bijective swizzle: 512 blocks, 8 XCDs, 64 contiguous per XCD
    int bid = blockIdx.x;
    int swz = (bid & 7) * 64 + (bid >> 3);
    const int bm = swz >> 4;            // 0..31
    const int bn = swz & 15;            // 0..15

    // ---- staging addressing: chunk c in {tid, tid+512}; row=c>>3, kc swz ----
    const int row0 = tid >> 3;                       // 0..63
    const int kc0  = (tid & 7) ^ (row0 & 7);         // source-side XOR swizzle
    const size_t CH2 = (size_t)64 * IN_F;            // chunk1 = chunk0 + 64 rows
    const unsigned short* gA[2];
    const unsigned short* gB[2];
    gA[0] = A + (size_t)(bm * 256 +   0 + row0) * IN_F + kc0 * 8;
    gA[1] = A + (size_t)(bm * 256 + 128 + row0) * IN_F + kc0 * 8;
    gB[0] = B + (size_t)(bn * 256 +   0 + row0) * IN_F + kc0 * 8;
    gB[1] = B + (size_t)(bn * 256 + 128 + row0) * IN_F + kc0 * 8;
    const int ldst0 = tid * 16;

    // ---- read addressing ----
    const int l16 = lane & 15, quad = lane >> 4, x7 = l16 & 7;
    const int sw0 = ((quad ^ x7) << 4);                       // kh=0; kh=1 -> ^64
    const int aRd = wm * 16384 + l16 * 128;                   // + par*32768 + qm*8192 + m*2048
    const int bRd = 65536 + (wn >> 1) * 16384 + (wn & 1) * 8192 + l16 * 128;

    f32x4 acc[8][4];
    #pragma unroll
    for (int i = 0; i < 8; ++i)
        #pragma unroll
        for (int j = 0; j < 4; ++j)
            acc[i][j] = (f32x4){0.f, 0.f, 0.f, 0.f};
    bf16x8 af[4][2];
    bf16x8 bf[4][2];

    // ---- prologue: issue half-tiles #0..6 (tile0 full, tile1 B0,B1,A0) ----
    STAGE(0, 0, 0); STAGE(1, 0, 0); STAGE(2, 0, 0); STAGE(3, 0, 0);
    STAGE(0, 1, 1); STAGE(1, 1, 1); STAGE(2, 1, 1);
    WAIT_VM(6);          // 14 issued, <=6 outstanding -> tile0 (8 loads) landed
    BARRIER();

    // ---- main loop: t = 0..61 ----
    #pragma unroll 1
    for (int tt = 0; tt < 62; tt += 2) {
        KTILE(0, 0, 1, 1, 6);
        KTILE(1, 1, 1, 1, 6);
        gA[0] += 128; gA[1] += 128; gB[0] += 128; gB[1] += 128;  // +2 K-tiles
    }
    // ---- t = 62: stage last half-tile (#255), then full drain ----
    KTILE(0, 0, 1, 0, 0);
    // ---- t = 63: no stages, no waits ----
    KTILE(1, 1, 0, 0, -1);

    // ---- epilogue ----
    const float s = isc[0] * ws2[0];
    #pragma unroll
    for (int M = 0; M < 8; ++M) {
        int r0 = bm * 256 + wm * 128 + M * 16 + quad * 4;
        #pragma unroll
        for (int n = 0; n < 4; ++n) {
            int col = bn * 256 + wn * 64 + n * 16 + l16;
            float* cp = C + (size_t)r0 * OUT_F + col;
            #pragma unroll
            for (int r = 0; r < 4; ++r)
                cp[(size_t)r * OUT_F] = acc[M][n][r] * s;
        }
    }
}

// ---------------- launcher -------------------------------------------------
extern "C" void kernel_launch(void* const* d_in, const int* in_sizes, int n_in,
                              void* d_out, int out_size, void* d_ws, size_t ws_size,
                              hipStream_t stream) {
    const float* x   = (const float*)d_in[0];   // [8192, 4096] fp32
    const int*   wq  = (const int*)d_in[1];     // [4096, 2048] packed fp4 pairs
    const int*   wsb = (const int*)d_in[2];     // [4096, 256] e4m3 bits
    const float* ws2 = (const float*)d_in[3];   // scalar
    const float* isc = (const float*)d_in[4];   // scalar
    float* out = (float*)d_out;                 // [8192, 4096] fp32

    unsigned short* Aq = (unsigned short*)d_ws;                          // 64 MB
    unsigned short* Wd = (unsigned short*)d_ws + (size_t)MROWS * IN_F;   // 32 MB

    static int attr_done = 0;
    if (!attr_done) {
        hipFuncSetAttribute(reinterpret_cast<const void*>(gemm256),
                            hipFuncAttributeMaxDynamicSharedMemorySize, 131072);
        attr_done = 1;
    }

    quant_act_kernel<<<32768, 256, 0, stream>>>(x, isc, Aq);
    dequant_w_kernel<<<8192, 256, 0, stream>>>(wq, wsb, Wd);
    gemm256<<<512, 512, 131072, stream>>>(Aq, Wd, out, isc, ws2);

    (void)in_sizes; (void)n_in; (void)out_size; (void)ws_size;
}

// Round 3
// 450.842 us; speedup vs baseline: 1.0001x; 1.0001x over previous
//
#include <hip/hip_runtime.h>
#include <stdint.h>

#define IN_F  4096
#define OUT_F 4096
#define MROWS 8192            // 4 * 2048

typedef __bf16 bf16x8 __attribute__((ext_vector_type(8)));
typedef float  f32x4  __attribute__((ext_vector_type(4)));

// ---------------- numeric helpers (replicate reference rounding) -----------

__device__ __forceinline__ float e4m3_round_dev(float x) {
    x = fminf(x, 448.0f);                 // x >= 0 by construction (amax)
    float lo, hi;
    if (x < 0.015625f) {                  // below 2^-6: denormal grid, step 2^-9
        lo = floorf(x * 512.0f) * 0.001953125f;
        hi = lo + 0.001953125f;
    } else {
        unsigned u = __float_as_uint(x);
        int E = (int)((u >> 23) & 0xFF) - 127;                    // 2^E <= x < 2^(E+1)
        float step  = __uint_as_float((unsigned)(E + 124) << 23); // 2^(E-3)
        float istep = __uint_as_float((unsigned)(130 - E) << 23); // 2^(3-E), exact
        lo = floorf(x * istep) * step;    // exact pow2 scaling
        hi = lo + step;
    }
    return (x - lo <= hi - x) ? lo : hi;
}

__device__ __forceinline__ float e4m3_decode_dev(int bits) {
    int e = (bits >> 3) & 15;
    int m = bits & 7;
    float mag;
    if (e == 0) mag = (float)m * 0.001953125f;  // m/8 * 2^-6
    else        mag = (1.0f + (float)m * 0.125f) * __uint_as_float((unsigned)(e + 120) << 23); // 2^(e-7)
    return (bits & 0x80) ? -mag : mag;
}

__device__ __forceinline__ float fp4_round_dev(float y) {
    float a = fminf(fabsf(y), 6.0f);
    float v;
    if (a < 1.75f) {
        if (a < 0.75f) v = (a < 0.25f) ? 0.0f : 0.5f;
        else           v = (a < 1.25f) ? 1.0f : 1.5f;
    } else {
        if (a < 3.5f)  v = (a < 2.5f) ? 2.0f : 3.0f;
        else           v = (a < 5.0f) ? 4.0f : 6.0f;
    }
    return copysignf(v, y);
}

__device__ __forceinline__ float fp4_decode_dev(int c) {
    int e = (c >> 1) & 3, m = c & 1;
    float mag = (e == 0) ? 0.5f * (float)m
                         : (1.0f + 0.5f * (float)m) * __uint_as_float((unsigned)(e + 126) << 23); // 2^(e-1)
    return (c & 8) ? -mag : mag;
}

__device__ __forceinline__ unsigned pack_bf16x2(float a, float b) {
    return (__float_as_uint(a) >> 16) | ((__float_as_uint(b) >> 16) << 16);
}

// ---------------- kernel 1: activation quant-dequant (verified) ------------
__global__ __launch_bounds__(256) void quant_act_kernel(
    const float* __restrict__ x, const float* __restrict__ in_scale,
    unsigned short* __restrict__ Aq)
{
    int t = blockIdx.x * 256 + threadIdx.x;   // thread id; 4 elems each
    const float isc = in_scale[0];
    float4 v = ((const float4*)x)[t];

    float a = fmaxf(fmaxf(fabsf(v.x), fabsf(v.y)), fmaxf(fabsf(v.z), fabsf(v.w)));
    a = fmaxf(a, __shfl_xor(a, 1));
    a = fmaxf(a, __shfl_xor(a, 2));           // group (4 lanes) amax

    float bscale = e4m3_round_dev(a / (6.0f * isc));  // IEEE div, as reference
    float eff = bscale * isc;
    float safe = (eff > 0.0f) ? eff : 1.0f;
    float inv = 1.0f / safe;                          // IEEE div

    unsigned o0 = pack_bf16x2(fp4_round_dev(v.x * inv) * bscale,
                              fp4_round_dev(v.y * inv) * bscale);
    unsigned o1 = pack_bf16x2(fp4_round_dev(v.z * inv) * bscale,
                              fp4_round_dev(v.w * inv) * bscale);
    ((uint2*)Aq)[t] = make_uint2(o0, o1);
}

// ---------------- kernel 2: weight dequant (verified) ----------------------
__global__ __launch_bounds__(256) void dequant_w_kernel(
    const int* __restrict__ wq, const int* __restrict__ wsb,
    unsigned short* __restrict__ Wd)
{
    int t = blockIdx.x * 256 + threadIdx.x;
    float scale = e4m3_decode_dev(wsb[t >> 1]);
    int4 b = ((const int4*)wq)[t];
    int bytes[4] = { b.x, b.y, b.z, b.w };
    unsigned out[4];
    #pragma unroll
    for (int i = 0; i < 4; i++) {
        int by = bytes[i];
        float v0 = fp4_decode_dev(by & 15) * scale;
        float v1 = fp4_decode_dev((by >> 4) & 15) * scale;
        out[i] = pack_bf16x2(v0, v1);
    }
    ((uint4*)Wd)[t] = make_uint4(out[0], out[1], out[2], out[3]);
}

// ---------------- kernel 3: bf16 GEMM, 256x256 tile, 1-barrier phases ------
//
// C[m,n] = s * sum_k A'[m,k] * W'[n,k],  s = input_scale * ws2
//
// 512 threads = 8 waves (2 M x 4 N); per-wave output 128x64.
// LDS 128 KiB: A,B each 2 parities x 2 half-slots of [128 rows][64 cols] bf16.
//
// ONE barrier per phase (4/K-tile, was 8). Phase p = [reads_p; stages_p;
// (vmcnt); BARRIER_p; lgkm0; MFMA_p]. WAR safety rule: a stage in phase p+2
// targeting a slot last READ in phase p is safe, because every wave executes
// lgkm0_p (draining its reads) before reaching BARRIER_{p+1}, and the stage
// issues only after BARRIER_{p+1}.
//
// Per K-tile t (par = t&1):
//   ph0: read B01 + A-qm0 (12) | stage Ah0(t+1), Bh1(t+1) | Q(0,0)
//   ph1: read B23 (4)          | stage Ah1(t+1)           | Q(0,1)
//   ph2: read A-qm1 (8)        | --                       | Q(1,0)
//   ph3: --                    | stage Bh0(t+2) ; vmcnt(2)| Q(1,1)
// Deadlines: B slots last-read ph1 -> Bh0 overwrite @ph3 (slack2), Bh1 @
// (t+1,0) (slack3). A slots last-read ph2 -> overwrites @(t+1,ph0/1) (slack2).
// RAW: latest load needed by tile t+1 is Ah1(t+1) @(t,1); loads after it =
// Bh0(t+2) @(t,3) = 2 -> vmcnt(2) once per K-tile. Tail: t=62 suppresses the
// ph3 stage so it must drain with vmcnt(0); t=63 stages nothing.
//
// XOR chunk swizzle (kc ^ row&7) on the global-source side (verified: zero
// bank conflicts).

__device__ __forceinline__ void gload16(const void* g, void* l) {
    __builtin_amdgcn_global_load_lds((__attribute__((address_space(1))) void*)g,
                                     (__attribute__((address_space(3))) void*)l,
                                     16, 0, 0);
}

#define BARRIER() __builtin_amdgcn_s_barrier()
#define WAIT_LGKM0() do { asm volatile("s_waitcnt lgkmcnt(0)" ::: "memory"); \
                          __builtin_amdgcn_sched_barrier(0); } while (0)
#define WAIT_VM(n) asm volatile("s_waitcnt vmcnt(" #n ")" ::: "memory")

// stage half-tile q (0=B-h0,1=B-h1,2=A-h0,3=A-h1) of DATA parity par,
// K-tile offset dt (in tiles) from the current pointer base.
#define STAGE(q, par, dt) do {                                                 \
    const unsigned short* g_ = ((q) >= 2 ? gA[(q)-2] : gB[(q)]) + (dt) * 64;   \
    char* l_ = ldsb + ((q) >= 2 ? (par)*32768 + ((q)-2)*16384                  \
                                : 65536 + (par)*32768 + (q)*16384) + ldst0;    \
    gload16(g_, l_);                                                           \
    gload16(g_ + CH2, l_ + 8192);                                              \
} while (0)

#define LOADA(par, qm) do {                                                    \
    const char* pa_ = ldsb + (par)*32768 + aRd + (qm)*8192;                    \
    _Pragma("unroll") for (int m_ = 0; m_ < 4; ++m_) {                         \
        af[m_][0] = *(const bf16x8*)(pa_ + m_*2048 + sw0);                     \
        af[m_][1] = *(const bf16x8*)(pa_ + m_*2048 + (sw0 ^ 64));              \
    }                                                                          \
} while (0)

#define LOADB01(par) do {                                                      \
    const char* pb_ = ldsb + (par)*32768 + bRd;                                \
    _Pragma("unroll") for (int n_ = 0; n_ < 2; ++n_) {                         \
        bf[n_][0] = *(const bf16x8*)(pb_ + n_*2048 + sw0);                     \
        bf[n_][1] = *(const bf16x8*)(pb_ + n_*2048 + (sw0 ^ 64));              \
    }                                                                          \
} while (0)

#define LOADB23(par) do {                                                      \
    const char* pb_ = ldsb + (par)*32768 + bRd;                                \
    _Pragma("unroll") for (int n_ = 2; n_ < 4; ++n_) {                         \
        bf[n_][0] = *(const bf16x8*)(pb_ + n_*2048 + sw0);                     \
        bf[n_][1] = *(const bf16x8*)(pb_ + n_*2048 + (sw0 ^ 64));              \
    }                                                                          \
} while (0)

#define MFMAQ(qm, qn) do {                                                     \
    __builtin_amdgcn_s_setprio(1);                                             \
    _Pragma("unroll") for (int m_ = 0; m_ < 4; ++m_)                           \
      _Pragma("unroll") for (int n_ = 0; n_ < 2; ++n_)                         \
        _Pragma("unroll") for (int kh_ = 0; kh_ < 2; ++kh_)                    \
          acc[(qm)*4 + m_][(qn)*2 + n_] =                                      \
            __builtin_amdgcn_mfma_f32_16x16x32_bf16(                           \
              af[m_][kh_], bf[(qn)*2 + n_][kh_],                               \
              acc[(qm)*4 + m_][(qn)*2 + n_], 0, 0, 0);                         \
    __builtin_amdgcn_s_setprio(0);                                             \
} while (0)

// One K-tile, 4 phases, 1 barrier each. SN: stage next-tile A+Bh1 slots.
// SB2: stage tile+2 Bh0. VMODE: 2 = steady vmcnt(2), 0 = drain, -1 = none.
#define KTILE(par, DT, SN, SB2, VMODE) do {                                    \
    /* ph0 */                                                                  \
    LOADB01(par); LOADA(par, 0);                                               \
    if (SN) { STAGE(2, (par) ^ 1, (DT) + 1); STAGE(1, (par) ^ 1, (DT) + 1); }  \
    BARRIER(); WAIT_LGKM0();                                                   \
    MFMAQ(0, 0);                                                               \
    /* ph1 */                                                                  \
    LOADB23(par);                                                              \
    if (SN) STAGE(3, (par) ^ 1, (DT) + 1);                                     \
    BARRIER(); WAIT_LGKM0();                                                   \
    MFMAQ(0, 1);                                                               \
    /* ph2 */                                                                  \
    LOADA(par, 1);                                                             \
    BARRIER(); WAIT_LGKM0();                                                   \
    MFMAQ(1, 0);                                                               \
    /* ph3 */                                                                  \
    if (SB2) STAGE(0, (par), (DT) + 2);                                        \
    if ((VMODE) == 2) { WAIT_VM(2); } else if ((VMODE) == 0) { WAIT_VM(0); }   \
    BARRIER();                                                                 \
    MFMAQ(1, 1);                                                               \
} while (0)

__global__ __launch_bounds__(512, 2) void gemm256(
    const unsigned short* __restrict__ A, const unsigned short* __restrict__ B,
    float* __restrict__ C, const float* __restrict__ isc,
    const float* __restrict__ ws2)
{
    extern __shared__ __align__(16) char lds[];
    char* const ldsb = lds;

    const int tid  = threadIdx.x;
    const int lane = tid & 63;
    const int w    = tid >> 6;          // 0..7
    const int wm   = w >> 2;            // 0..1  (M half)
    const int wn   = w & 3;             // 0..3  (N quarter)

    // XCD-bijective swizzle: 512 blocks, 8 XCDs, 64 contiguous per XCD
    int bid = blockIdx.x;
    int swz = (bid & 7) * 64 + (bid >> 3);
    const int bm = swz >> 4;            // 0..31
    const int bn = swz & 15;            // 0..15

    // ---- staging addressing: chunk c in {tid, tid+512}; row=c>>3, kc swz ----
    const int row0 = tid >> 3;                       // 0..63
    const int kc0  = (tid & 7) ^ (row0 & 7);         // source-side XOR swizzle
    const size_t CH2 = (size_t)64 * IN_F;            // chunk1 = chunk0 + 64 rows
    const unsigned short* gA[2];
    const unsigned short* gB[2];
    gA[0] = A + (size_t)(bm * 256 +   0 + row0) * IN_F + kc0 * 8;
    gA[1] = A + (size_t)(bm * 256 + 128 + row0) * IN_F + kc0 * 8;
    gB[0] = B + (size_t)(bn * 256 +   0 + row0) * IN_F + kc0 * 8;
    gB[1] = B + (size_t)(bn * 256 + 128 + row0) * IN_F + kc0 * 8;
    const int ldst0 = tid * 16;

    // ---- read addressing ----
    const int l16 = lane & 15, quad = lane >> 4, x7 = l16 & 7;
    const int sw0 = ((quad ^ x7) << 4);                       // kh=0; kh=1 -> ^64
    const int aRd = wm * 16384 + l16 * 128;                   // + par*32768 + qm*8192 + m*2048
    const int bRd = 65536 + (wn >> 1) * 16384 + (wn & 1) * 8192 + l16 * 128;

    f32x4 acc[8][4];
    #pragma unroll
    for (int i = 0; i < 8; ++i)
        #pragma unroll
        for (int j = 0; j < 4; ++j)
            acc[i][j] = (f32x4){0.f, 0.f, 0.f, 0.f};
    bf16x8 af[4][2];
    bf16x8 bf[4][2];

    // ---- prologue: Bh0(0), Ah0(0), Bh1(0), Ah1(0), Bh0(1); vmcnt(2) -------
    STAGE(0, 0, 0); STAGE(2, 0, 0); STAGE(1, 0, 0); STAGE(3, 0, 0);
    STAGE(0, 1, 1);
    WAIT_VM(2);          // 10 issued, <=2 outstanding -> tile0 (8 loads) landed
    BARRIER();

    // ---- main loop: t = 0..61 ----
    #pragma unroll 1
    for (int tt = 0; tt < 62; tt += 2) {
        KTILE(0, 0, 1, 1, 2);
        KTILE(1, 1, 1, 1, 2);
        gA[0] += 128; gA[1] += 128; gB[0] += 128; gB[1] += 128;  // +2 K-tiles
    }
    // ---- t = 62: stage tile-63 A/Bh1, suppress Bh0(64), full drain ----
    KTILE(0, 0, 1, 0, 0);
    // ---- t = 63: no stages, no waits ----
    KTILE(1, 1, 0, 0, -1);

    // ---- epilogue ----
    const float s = isc[0] * ws2[0];
    #pragma unroll
    for (int M = 0; M < 8; ++M) {
        int r0 = bm * 256 + wm * 128 + M * 16 + quad * 4;
        #pragma unroll
        for (int n = 0; n < 4; ++n) {
            int col = bn * 256 + wn * 64 + n * 16 + l16;
            float* cp = C + (size_t)r0 * OUT_F + col;
            #pragma unroll
            for (int r = 0; r < 4; ++r)
                cp[(size_t)r * OUT_F] = acc[M][n][r] * s;
        }
    }
}

// ---------------- launcher -------------------------------------------------
extern "C" void kernel_launch(void* const* d_in, const int* in_sizes, int n_in,
                              void* d_out, int out_size, void* d_ws, size_t ws_size,
                              hipStream_t stream) {
    const float* x   = (const float*)d_in[0];   // [8192, 4096] fp32
    const int*   wq  = (const int*)d_in[1];     // [4096, 2048] packed fp4 pairs
    const int*   wsb = (const int*)d_in[2];     // [4096, 256] e4m3 bits
    const float* ws2 = (const float*)d_in[3];   // scalar
    const float* isc = (const float*)d_in[4];   // scalar
    float* out = (float*)d_out;                 // [8192, 4096] fp32

    unsigned short* Aq = (unsigned short*)d_ws;                          // 64 MB
    unsigned short* Wd = (unsigned short*)d_ws + (size_t)MROWS * IN_F;   // 32 MB

    static int attr_done = 0;
    if (!attr_done) {
        hipFuncSetAttribute(reinterpret_cast<const void*>(gemm256),
                            hipFuncAttributeMaxDynamicSharedMemorySize, 131072);
        attr_done = 1;
    }

    quant_act_kernel<<<32768, 256, 0, stream>>>(x, isc, Aq);
    dequant_w_kernel<<<8192, 256, 0, stream>>>(wq, wsb, Wd);
    gemm256<<<512, 512, 131072, stream>>>(Aq, Wd, out, isc, ws2);

    (void)in_sizes; (void)n_in; (void)out_size; (void)ws_size;
}